// Round 10
// baseline (716.987 us; speedup 1.0000x reference)
//
#include <hip/hip_runtime.h>
#include <stdint.h>
#include <math.h>

#define NN 10000
#define NE 30000
#define NG 50
#define NH 8

typedef _Float16 f16;
typedef _Float16 f16x2 __attribute__((ext_vector_type(2)));
typedef _Float16 f16x4 __attribute__((ext_vector_type(4)));
typedef _Float16 f16x8 __attribute__((ext_vector_type(8)));
typedef float f32x4 __attribute__((ext_vector_type(4)));

// ---------------- helpers ----------------
__device__ inline void async16(f16* l, const f16* g) {
    __builtin_amdgcn_global_load_lds((const __attribute__((address_space(1))) void*)g,
                                     (__attribute__((address_space(3))) void*)l, 16, 0, 0);
}

// ---------------- CSR build ----------------
__global__ void hist_kernel(const int* __restrict__ dst, int* __restrict__ deg, int E) {
    int e = blockIdx.x * blockDim.x + threadIdx.x;
    if (e < E) atomicAdd(&deg[dst[e]], 1);
}

__global__ __launch_bounds__(1024) void scan_kernel(const int* __restrict__ deg, int* __restrict__ offs, int n) {
    __shared__ int tmp[1024];
    __shared__ int carry;
    if (threadIdx.x == 0) { carry = 0; offs[0] = 0; }
    __syncthreads();
    for (int base = 0; base < n; base += 1024) {
        int i = base + (int)threadIdx.x;
        int v = (i < n) ? deg[i] : 0;
        tmp[threadIdx.x] = v;
        __syncthreads();
        for (int d = 1; d < 1024; d <<= 1) {
            int t = 0;
            if ((int)threadIdx.x >= d) t = tmp[threadIdx.x - d];
            __syncthreads();
            if ((int)threadIdx.x >= d) tmp[threadIdx.x] += t;
            __syncthreads();
        }
        if (i < n) offs[i + 1] = carry + tmp[threadIdx.x];
        __syncthreads();
        if (threadIdx.x == 0) carry += tmp[1023];
        __syncthreads();
    }
}

__global__ void copy_int(const int* __restrict__ a, int* __restrict__ b, int n) {
    int i = blockIdx.x * blockDim.x + threadIdx.x;
    if (i < n) b[i] = a[i];
}

__global__ void scatter_kernel(const int* __restrict__ src, const int* __restrict__ dst,
                               int* __restrict__ cursor, int* __restrict__ srcCSR, int E) {
    int e = blockIdx.x * blockDim.x + threadIdx.x;
    if (e < E) {
        int p = atomicAdd(&cursor[dst[e]], 1);
        srcCSR[p] = src[e];
    }
}

// per-segment insertion sort -> deterministic CSR (fixed fp32 summation orders)
__global__ void sort_csr(const int* __restrict__ offs, int* __restrict__ srcCSR) {
    int n = blockIdx.x * blockDim.x + threadIdx.x;
    if (n >= NN) return;
    int s = offs[n], e = offs[n + 1];
    for (int i = s + 1; i < e; ++i) {
        int v = srcCSR[i];
        int j = i - 1;
        while (j >= s && srcCSR[j] > v) { srcCSR[j + 1] = srcCSR[j]; --j; }
        srcCSR[j + 1] = v;
    }
}

__global__ void goffs_kernel(const int* __restrict__ batch, int* __restrict__ goffs) {
    int g = threadIdx.x;
    if (g > NG) return;
    int lo = 0, hi = NN;
    while (lo < hi) {
        int mid = (lo + hi) >> 1;
        if (batch[mid] < g) lo = mid + 1; else hi = mid;
    }
    goffs[g] = lo;
}

// ---------------- conversions / weight prep ----------------
__global__ void cvt_f16_kernel(const float* __restrict__ in, f16* __restrict__ out, int n) {
    int i = blockIdx.x * blockDim.x + threadIdx.x;
    if (i < n) out[i] = (f16)in[i];
}

// Build Bt [Ntot][K] f16 (transposed, concatenated W0|W1|zero-pad) + bias [Ntot] f32.
__global__ void prep2(const float* __restrict__ W0, const float* __restrict__ b0, int n0,
                      const float* __restrict__ W1, const float* __restrict__ b1, int n1,
                      f16* __restrict__ Bt, float* __restrict__ bias,
                      int K, int kshift, int Ntot) {
    int tid = blockIdx.x * blockDim.x + threadIdx.x;
    if (tid >= (Ntot << kshift)) return;
    int n = tid >> kshift;
    int k = tid & (K - 1);
    float w = 0.0f;
    if (n < n0) w = W0[(size_t)k * n0 + n];
    else if (n < n0 + n1) w = W1[(size_t)k * n1 + (n - n0)];
    Bt[tid] = (f16)w;
    if (k == 0) bias[n] = (n < n0) ? b0[n] : ((n < n0 + n1) ? b1[n - n0] : 0.0f);
}

// u/v/c columns of the Y transform: row 8fin+h = Wq_h@kb_h (bias c_h=qb_h.kb_h),
// row 8fin+8+h = Wk_h@qb_h (bias 0). One thread per (k, h, isV).
__global__ void prepU(const float* __restrict__ qw, const float* __restrict__ qb,
                      const float* __restrict__ kw, const float* __restrict__ kb,
                      f16* __restrict__ BtY, float* __restrict__ biasY,
                      int fin, int hc, int C) {
    int tid = blockIdx.x * blockDim.x + threadIdx.x;
    if (tid >= fin * 16) return;
    int k = tid >> 4;
    int idx = tid & 15;
    int h = idx & 7, isV = idx >> 3;
    const float* W = isV ? kw : qw;
    const float* bvec = isV ? qb : kb;
    float s = 0.0f;
    for (int c = 0; c < C; ++c) s += W[(size_t)k * hc + h * C + c] * bvec[h * C + c];
    BtY[(size_t)(8 * fin + isV * 8 + h) * fin + k] = (f16)s;
    if (k == 0 && isV == 0) {
        float cc = 0.0f;
        for (int c = 0; c < C; ++c) cc += qb[h * C + c] * kb[h * C + c];
        biasY[8 * fin + h] = cc;
    }
}

// ---------------- GEMM: C[M,Np] = A @ Bt^T + bias, f16 out (generalized strides) ----
// 128x128 tile, BK=32, 3-stage ring prefetch (distance 2), s_waitcnt vmcnt(4) +
// raw s_barrier (prefetch survives the barrier), XOR-swizzled k-chunks,
// swapped-operand MFMA, union-LDS epilogue. Per-z offsets for batched (per-head) use.
__global__ __launch_bounds__(256) void gemm128(const f16* __restrict__ A, int lda, int zA,
                                               const f16* __restrict__ Bt, int ldb, int zB,
                                               const float* __restrict__ bias,
                                               f16* __restrict__ C, int ldc, int zC,
                                               float* __restrict__ Sf,
                                               int M, int Np, int K, int hcS, int Sw) {
    __shared__ f16 smem[24576];   // 48 KB = 3 stages x (A 4096 + B 4096 f16)
    const int rm = blockIdx.x * 128;
    if (rm >= M) return;          // padded grid column (XCD-stable mapping)
    A  += (size_t)blockIdx.z * zA;
    Bt += (size_t)blockIdx.z * zB;
    C  += (size_t)blockIdx.z * zC;
    const int tid  = threadIdx.x;
    const int lane = tid & 63;
    const int wave = tid >> 6;
    const int l16  = lane & 15;
    const int quad = lane >> 4;
    const int cn   = blockIdx.y * 128;
    const int wrow = (wave >> 1) * 64;
    const int wcol = (wave & 1) * 64;

    const int rS  = tid >> 2;
    const int kc  = ((tid & 3) ^ ((tid >> 3) & 3)) << 3;
    int rowA0 = rm + rS;       if (rowA0 >= M) rowA0 = M - 1;
    int rowA1 = rm + rS + 64;  if (rowA1 >= M) rowA1 = M - 1;
    const f16* gA0 = A + (size_t)rowA0 * lda + kc;
    const f16* gA1 = A + (size_t)rowA1 * lda + kc;
    const f16* gB0 = Bt + (size_t)(cn + rS) * ldb + kc;
    const f16* gB1 = Bt + (size_t)(cn + rS + 64) * ldb + kc;

    const int swf = (l16 >> 1) & 3;
    const int rdAoff = (wrow + l16) * 32 + ((quad ^ swf) << 3);
    const int rdBoff = 4096 + (wcol + l16) * 32 + ((quad ^ swf) << 3);

    f32x4 acc[4][4] = {};

    auto stage_load = [&](int slot) {
        f16* base = smem + slot * 8192;
        async16(base + tid * 8, gA0);
        async16(base + tid * 8 + 2048, gA1);
        async16(base + 4096 + tid * 8, gB0);
        async16(base + 4096 + tid * 8 + 2048, gB1);
        gA0 += 32; gA1 += 32; gB0 += 32; gB1 += 32;
    };

    const int NI = K >> 5;
    stage_load(0);
    stage_load(1);

    int slot = 0;
    for (int i = 0; i < NI; ++i) {
        if (i + 1 < NI) asm volatile("s_waitcnt vmcnt(4)" ::: "memory");
        else            asm volatile("s_waitcnt vmcnt(0)" ::: "memory");
        asm volatile("s_barrier" ::: "memory");
        if (i + 2 < NI) {
            int s2 = slot + 2; if (s2 >= 3) s2 -= 3;
            stage_load(s2);
        }
        const f16* sb = smem + slot * 8192;
        f16x8 av[4], bv[4];
#pragma unroll
        for (int ii = 0; ii < 4; ++ii) av[ii] = *(const f16x8*)(sb + rdAoff + ii * 512);
#pragma unroll
        for (int j = 0; j < 4; ++j) bv[j] = *(const f16x8*)(sb + rdBoff + j * 512);
#pragma unroll
        for (int ii = 0; ii < 4; ++ii)
#pragma unroll
            for (int j = 0; j < 4; ++j)
                acc[ii][j] = __builtin_amdgcn_mfma_f32_16x16x32_f16(bv[j], av[ii], acc[ii][j], 0, 0, 0);
        ++slot; if (slot == 3) slot = 0;
    }
    __syncthreads();

    f16* sC = smem;    // 64 x 136 f16
    for (int round = 0; round < 2; ++round) {
        if ((wave >> 1) == round) {
#pragma unroll
            for (int j = 0; j < 4; ++j) {
                const int cb = wcol + j * 16 + quad * 4;
                const float4 bb = *(const float4*)(bias + cn + cb);
#pragma unroll
                for (int i = 0; i < 4; ++i) {
                    const int r = i * 16 + l16;
                    float v0 = acc[i][j][0] + bb.x;
                    float v1 = acc[i][j][1] + bb.y;
                    float v2 = acc[i][j][2] + bb.z;
                    float v3 = acc[i][j][3] + bb.w;
                    f16x4 o;
                    o[0] = (f16)v0; o[1] = (f16)v1; o[2] = (f16)v2; o[3] = (f16)v3;
                    *(f16x4*)(sC + r * 136 + cb) = o;
                    if (Sf) {
                        const int sc = cn + cb - hcS;
                        if (sc >= 0 && sc < Sw) {
                            const int grow = rm + round * 64 + r;
                            if (grow < M) {
                                float4 sv = { v0, v1, v2, v3 };
                                *(float4*)(Sf + (size_t)grow * Sw + sc) = sv;
                            }
                        }
                    }
                }
            }
        }
        __syncthreads();
#pragma unroll
        for (int it = 0; it < 4; ++it) {
            const int r = it * 16 + (tid >> 4);
            const int ch = tid & 15;
            const int grow = rm + round * 64 + r;
            if (grow < M) {
                f16x8 v = *(const f16x8*)(sC + r * 136 + ch * 8);
                *(f16x8*)(C + (size_t)grow * ldc + cn + ch * 8) = v;
            }
        }
        __syncthreads();
    }
}

// ---------------- layer-1 alpha via Y = X@M_h trick ----------------
// alpha[e,h] = scale * ( Y_h[n] . x[src] + u[n,h] + v[src,h] )   (c_h folded in u bias)
// Y row layout: [h*fin + k] for k<fin, then u[8], then v[8].
__global__ __launch_bounds__(256) void alpha_fused_y(const f16* __restrict__ Y, const f16* __restrict__ X,
                                                     const int* __restrict__ offs,
                                                     const int* __restrict__ srcCSR,
                                                     float* __restrict__ alphaW,
                                                     int strideY, int fin, float scale) {
    const int n = blockIdx.x;
    const int e0 = offs[n];
    int d = offs[n + 1] - e0;
    if (d > 256) d = 256;

    __shared__ __align__(16) f16 sy[1024];   // 8*fin (fin=128)
    __shared__ float sew[256 * NH];
    __shared__ float sv[256 * NH];
    __shared__ int sed[256];
    __shared__ float su[NH];
    const int tid = threadIdx.x;

    const f16* Yn = Y + (size_t)n * strideY;
    for (int c = tid; c < fin; c += 256) ((f16x8*)sy)[c] = ((const f16x8*)Yn)[c];
    if (tid < NH) su[tid] = (float)Yn[8 * fin + tid];
    for (int e = tid; e < d; e += 256) {
        int s = srcCSR[e0 + e];
        sed[e] = s;
        f16x8 vv = *(const f16x8*)(Y + (size_t)s * strideY + 8 * fin + 8);
#pragma unroll
        for (int t = 0; t < 8; ++t) sv[e * NH + t] = (float)vv[t];
    }
    __syncthreads();

    const int wv = tid >> 6, lane = tid & 63;
    const int cph = fin >> 3;          // x-chunks per head (16 for fin=128)
    const int csh = __ffs(cph) - 1;
    const int passes = fin >> 6;       // total chunks (8*fin/8 = fin) / 64
    for (int e = wv; e < d; e += 4) {
        const f16x8* kg = (const f16x8*)(X + (size_t)sed[e] * fin);
        for (int p = 0; p < passes; ++p) {
            const int ci = p * 64 + lane;
            const int head = ci >> csh;
            const int kcn = ci & (cph - 1);
            f16x8 yv = ((const f16x8*)sy)[ci];
            f16x8 xv = kg[kcn];
            float acc = 0.0f;
#pragma unroll
            for (int t = 0; t < 8; ++t) acc += (float)yv[t] * (float)xv[t];
            for (int o = cph >> 1; o > 0; o >>= 1) acc += __shfl_down(acc, o, cph);
            if ((lane & (cph - 1)) == 0)
                sew[e * NH + head] = (acc + su[head] + sv[e * NH + head]) * scale;
        }
    }
    __syncthreads();

    if (tid < NH) {
        const int h = tid;
        float m = -3.0e38f;
        for (int e = 0; e < d; ++e) m = fmaxf(m, sew[e * NH + h]);
        float den = 0.0f;
        for (int e = 0; e < d; ++e) {
            float ex = __expf(sew[e * NH + h] - m);
            sew[e * NH + h] = ex;
            den += ex;
        }
        float inv = 1.0f / (fmaxf(den, 1e-16f) * (float)NH);
        for (int e = 0; e < d; ++e) sew[e * NH + h] *= inv;
    }
    __syncthreads();

    for (int i = tid; i < d * NH; i += 256) alphaW[(size_t)e0 * NH + i] = sew[i];
}

// ---------------- layers 2,3: edge logits + softmax from materialized Q|K ----------
__global__ __launch_bounds__(256) void alpha_fused(const f16* __restrict__ QK,
                                                   const int* __restrict__ offs,
                                                   const int* __restrict__ srcCSR,
                                                   float* __restrict__ alphaW,
                                                   int strideQK, int C, int hc, float scale) {
    const int n = blockIdx.x;
    const int e0 = offs[n];
    int d = offs[n + 1] - e0;
    if (d > 256) d = 256;

    __shared__ __align__(16) f16 sq[4096];
    __shared__ float sew[256 * NH];
    __shared__ int sed[256];
    const int tid = threadIdx.x;

    const f16x8* qg = (const f16x8*)(QK + (size_t)n * strideQK);
    const int qchunks = hc >> 3;
    for (int c = tid; c < qchunks; c += 256) ((f16x8*)sq)[c] = qg[c];
    for (int e = tid; e < d; e += 256) sed[e] = srcCSR[e0 + e];
    __syncthreads();

    const int wv = tid >> 6, lane = tid & 63;
    const int cph = C >> 3;
    const int passes = hc >> 9;
    for (int e = wv; e < d; e += 4) {
        const f16x8* kg = (const f16x8*)(QK + (size_t)sed[e] * strideQK + hc);
        for (int p = 0; p < passes; ++p) {
            const int ci = p * 64 + lane;
            f16x8 qv = ((const f16x8*)sq)[ci];
            f16x8 kv = kg[ci];
            float acc = 0.0f;
#pragma unroll
            for (int t = 0; t < 8; ++t) acc += (float)qv[t] * (float)kv[t];
            for (int o = cph >> 1; o > 0; o >>= 1) acc += __shfl_down(acc, o, cph);
            if ((lane & (cph - 1)) == 0) {
                const int head = ci / cph;
                sew[e * NH + head] = acc * scale;
            }
        }
    }
    __syncthreads();

    if (tid < NH) {
        const int h = tid;
        float m = -3.0e38f;
        for (int e = 0; e < d; ++e) m = fmaxf(m, sew[e * NH + h]);
        float den = 0.0f;
        for (int e = 0; e < d; ++e) {
            float ex = __expf(sew[e * NH + h] - m);
            sew[e * NH + h] = ex;
            den += ex;
        }
        float inv = 1.0f / (fmaxf(den, 1e-16f) * (float)NH);
        for (int e = 0; e < d; ++e) sew[e * NH + h] *= inv;
    }
    __syncthreads();

    for (int i = tid; i < d * NH; i += 256) alphaW[(size_t)e0 * NH + i] = sew[i];
}

// ---------------- per-node: weighted V aggregation + fp32 skip + ELU ----------------
__global__ __launch_bounds__(256) void node_agg(const f16* __restrict__ VS,
                                                const float* __restrict__ Sf,
                                                const int* __restrict__ offs,
                                                const int* __restrict__ srcCSR,
                                                const float* __restrict__ alphaW,
                                                float* __restrict__ hout, f16* __restrict__ houth,
                                                int C, int hc, int NpVS, int writeHout) {
    const int n = blockIdx.x;
    const int e0 = offs[n];
    int d = offs[n + 1] - e0;
    if (d > 256) d = 256;

    __shared__ float sew[256 * NH];
    __shared__ int sed[256];
    __shared__ float sred[512];
    const int tid = threadIdx.x;

    for (int i = tid; i < d * NH; i += 256) sew[i] = alphaW[(size_t)e0 * NH + i];
    for (int e = tid; e < d; e += 256) sed[e] = srcCSR[e0 + e];
    __syncthreads();

    const int half = C >> 1;
    const int cp = tid & (half - 1);
    const int grp = tid / half;
    const int ngr = 256 / half;
    float a0 = 0.0f, a1 = 0.0f;
    for (int e = grp; e < d; e += ngr) {
        const unsigned int* vp = (const unsigned int*)(VS + (size_t)sed[e] * NpVS);
#pragma unroll
        for (int h = 0; h < NH; ++h) {
            float w = sew[e * NH + h];
            f16x2 vv = __builtin_bit_cast(f16x2, vp[((h * C) >> 1) + cp]);
            a0 += w * (float)vv.x;
            a1 += w * (float)vv.y;
        }
    }
    if (ngr > 1) {
        sred[tid] = a0;
        sred[256 + tid] = a1;
        __syncthreads();
        if (grp == 0) {
            for (int g = 1; g < ngr; ++g) {
                a0 += sred[g * half + cp];
                a1 += sred[256 + g * half + cp];
            }
        }
    }
    if (grp == 0) {
        const int c = cp * 2;
        const float* Sp = Sf + (size_t)n * C;
        float o0 = a0 + Sp[c];
        float o1 = a1 + Sp[c + 1];
        o0 = o0 > 0.0f ? o0 : (__expf(o0) - 1.0f);
        o1 = o1 > 0.0f ? o1 : (__expf(o1) - 1.0f);
        if (writeHout) {
            hout[(size_t)n * C + c] = o0;
            hout[(size_t)n * C + c + 1] = o1;
        }
        houth[(size_t)n * C + c] = (f16)o0;
        houth[(size_t)n * C + c + 1] = (f16)o1;
    }
}

// ---------------- fused pooling + final FC: one block per graph, no atomics ----
__global__ __launch_bounds__(256) void pool_graph(const float* __restrict__ h,
                                                  const float* __restrict__ gw, const float* __restrict__ gb,
                                                  const float* __restrict__ fcw, const float* __restrict__ fcb,
                                                  const int* __restrict__ goffs,
                                                  float* __restrict__ gbuf, float* __restrict__ out) {
    const int g = blockIdx.x;
    const int s = goffs[g], e = goffs[g + 1];
    const int tid = threadIdx.x;
    const int wv = tid >> 6, lane = tid & 63;

    __shared__ float red[256];
    __shared__ float pl[64];
    __shared__ float sden;

    if (e == s) {
        if (tid < 10) out[g * 10 + tid] = fcb[tid];
        return;
    }

    const float gwl = gw[lane];
    for (int n = s + wv; n < e; n += 4) {
        float acc = h[(size_t)n * 64 + lane] * gwl;
#pragma unroll
        for (int o = 32; o > 0; o >>= 1) acc += __shfl_down(acc, o, 64);
        if (lane == 0) gbuf[n] = acc + gb[0];
    }
    __syncthreads();

    float m = -3.0e38f;
    for (int n = s + tid; n < e; n += 256) m = fmaxf(m, gbuf[n]);
    red[tid] = m;
    __syncthreads();
    for (int o = 128; o > 0; o >>= 1) {
        if (tid < o) red[tid] = fmaxf(red[tid], red[tid + o]);
        __syncthreads();
    }
    m = red[0];
    __syncthreads();

    float sum = 0.0f;
    for (int n = s + tid; n < e; n += 256) {
        float ex = __expf(gbuf[n] - m);
        gbuf[n] = ex;
        sum += ex;
    }
    red[tid] = sum;
    __syncthreads();
    for (int o = 128; o > 0; o >>= 1) {
        if (tid < o) red[tid] += red[tid + o];
        __syncthreads();
    }
    if (tid == 0) sden = 1.0f / fmaxf(red[0], 1e-16f);
    __syncthreads();

    float acc = 0.0f;
    for (int n = s + wv; n < e; n += 4) acc += gbuf[n] * h[(size_t)n * 64 + lane];
    red[tid] = acc;
    __syncthreads();
    if (wv == 0) pl[lane] = (red[lane] + red[64 + lane] + red[128 + lane] + red[192 + lane]) * sden;
    __syncthreads();

    if (tid < 10) {
        float o = fcb[tid];
#pragma unroll
        for (int c = 0; c < 64; ++c) o += pl[c] * fcw[c * 10 + tid];
        out[g * 10 + tid] = o;
    }
}

// ---------------- host ----------------
extern "C" void kernel_launch(void* const* d_in, const int* in_sizes, int n_in,
                              void* d_out, int out_size, void* d_ws, size_t ws_size,
                              hipStream_t stream) {
    const float* x   = (const float*)d_in[0];
    const int* ei    = (const int*)d_in[1];
    const int* src   = ei;
    const int* dst   = ei + NE;
    const int* batch = (const int*)d_in[2];

    struct LayerW { int fin, C, hc; const float *qw,*qb,*kw,*kb,*vw,*vb,*sw,*sb; };
    LayerW LW[3];
    const int fins[3]   = {128, 512, 256};
    const int kshift[3] = {7, 9, 8};
    const int Cs[3]     = {512, 256, 64};
    const int NpVS[3]   = {4608, 2304, 640};  // hc + C padded to x128
    for (int l = 0; l < 3; ++l) {
        int b = 3 + 8 * l;
        LW[l].fin = fins[l]; LW[l].C = Cs[l]; LW[l].hc = Cs[l] * NH;
        LW[l].qw = (const float*)d_in[b + 0]; LW[l].qb = (const float*)d_in[b + 1];
        LW[l].kw = (const float*)d_in[b + 2]; LW[l].kb = (const float*)d_in[b + 3];
        LW[l].vw = (const float*)d_in[b + 4]; LW[l].vb = (const float*)d_in[b + 5];
        LW[l].sw = (const float*)d_in[b + 6]; LW[l].sb = (const float*)d_in[b + 7];
    }
    const float* gate_w = (const float*)d_in[27];
    const float* gate_b = (const float*)d_in[28];
    const float* fc_w   = (const float*)d_in[29];
    const float* fc_b   = (const float*)d_in[30];

    size_t off = 0;
    char* ws = (char*)d_ws;
    auto alloc = [&](size_t bytes) -> void* {
        void* p = ws + off;
        off = (off + bytes + 255) & ~(size_t)255;
        return p;
    };
    f16* BtQK   = (f16*)alloc((size_t)4096 * 512 * sizeof(f16));
    f16* BtVS   = (f16*)alloc((size_t)2304 * 512 * sizeof(f16));
    float* biasQK = (float*)alloc(8192 * sizeof(float));
    float* biasVS = (float*)alloc(4608 * sizeof(float));
    f16* QKbuf  = (f16*)alloc((size_t)NN * 4608 * sizeof(f16));    // Y / Q|K / V|S (per phase)
    float* Sf   = (float*)alloc((size_t)NN * 512 * sizeof(float)); // fp32 skip
    f16* xh     = (f16*)alloc((size_t)NN * 128 * sizeof(f16));
    f16* houth  = (f16*)alloc((size_t)NN * 512 * sizeof(f16));
    float* hf   = (float*)alloc((size_t)NN * 64 * sizeof(float));
    float* alphaW = (float*)alloc((size_t)NE * NH * sizeof(float));
    f16* qw16   = (f16*)alloc((size_t)128 * 4096 * sizeof(f16));   // layer-1 Wq f16 row-major
    f16* kw16   = (f16*)alloc((size_t)128 * 4096 * sizeof(f16));
    f16* BtY    = (f16*)alloc((size_t)1152 * 128 * sizeof(f16));   // M rows + u/v rows
    float* biasY = (float*)alloc(1152 * sizeof(float));
    float* zbias = (float*)alloc(512 * sizeof(float));
    int* deg    = (int*)alloc(NN * sizeof(int));
    int* offs   = (int*)alloc((NN + 1) * sizeof(int));
    int* cursor = (int*)alloc(NN * sizeof(int));
    int* srcCSR = (int*)alloc(NE * sizeof(int));
    int* goffs  = (int*)alloc((NG + 1) * sizeof(int));
    float* gbuf = (float*)alloc(NN * sizeof(float));
    if (off > ws_size) return;

    // CSR build (+ deterministic sort) + graph offsets
    hipMemsetAsync(deg, 0, NN * sizeof(int), stream);
    hipMemsetAsync(zbias, 0, 512 * sizeof(float), stream);
    hipMemsetAsync(biasY, 0, 1152 * sizeof(float), stream);
    hist_kernel<<<(NE + 255) / 256, 256, 0, stream>>>(dst, deg, NE);
    scan_kernel<<<1, 1024, 0, stream>>>(deg, offs, NN);
    copy_int<<<(NN + 255) / 256, 256, 0, stream>>>(offs, cursor, NN);
    scatter_kernel<<<(NE + 255) / 256, 256, 0, stream>>>(src, dst, cursor, srcCSR, NE);
    sort_csr<<<(NN + 255) / 256, 256, 0, stream>>>(offs, srcCSR);
    goffs_kernel<<<1, 64, 0, stream>>>(batch, goffs);

    cvt_f16_kernel<<<(NN * 128 + 255) / 256, 256, 0, stream>>>(x, xh, NN * 128);

    const int grid_m = 80;   // mult of 8: XCD = blockIdx.x % 8 invariant across y-passes
    const f16* Acur = xh;
    for (int l = 0; l < 3; ++l) {
        const int K = LW[l].fin, C = LW[l].C, hc = LW[l].hc;
        const int Np1 = NpVS[l];
        const float scale = 1.0f / sqrtf((float)C);

        if (l == 0) {
            // ---- layer 1: Y = X @ [M_h | u | v] trick (fin=128 << hc=4096) ----
            const int fin = 128, NtotY = 1152;
            cvt_f16_kernel<<<(fin * hc + 255) / 256, 256, 0, stream>>>(LW[0].qw, qw16, fin * hc);
            cvt_f16_kernel<<<(fin * hc + 255) / 256, 256, 0, stream>>>(LW[0].kw, kw16, fin * hc);
            // M rows: BtY[h*fin+j, k] = sum_c kw[j,hC+c] qw[k,hC+c]  (per-head GEMM via z)
            dim3 gm(1, 1, 8);
            gemm128<<<gm, 256, 0, stream>>>(kw16, hc, C, qw16, hc, C, zbias,
                                            BtY, fin, fin * fin, nullptr, fin, fin, C, 0, 0);
            prepU<<<(fin * 16 + 255) / 256, 256, 0, stream>>>(LW[0].qw, LW[0].qb, LW[0].kw, LW[0].kb,
                                                              BtY, biasY, fin, hc, C);
            // Y GEMM: [NN, NtotY]
            dim3 gy(grid_m, NtotY / 128);
            gemm128<<<gy, 256, 0, stream>>>(xh, fin, 0, BtY, fin, 0, biasY,
                                            QKbuf, NtotY, 0, nullptr, NN, NtotY, fin, 0, 0);
            alpha_fused_y<<<NN, 256, 0, stream>>>(QKbuf, xh, offs, srcCSR, alphaW,
                                                  NtotY, fin, scale);
        } else {
            // ---- layers 2,3: materialized Q|K path ----
            const int Np0 = 2 * hc;
            {
                int tot = Np0 << kshift[l];
                prep2<<<(tot + 255) / 256, 256, 0, stream>>>(LW[l].qw, LW[l].qb, hc,
                                                             LW[l].kw, LW[l].kb, hc,
                                                             BtQK, biasQK, K, kshift[l], Np0);
            }
            dim3 gqk(grid_m, Np0 / 128);
            gemm128<<<gqk, 256, 0, stream>>>(Acur, K, 0, BtQK, K, 0, biasQK,
                                             QKbuf, Np0, 0, nullptr, NN, Np0, K, 0, 0);
            alpha_fused<<<NN, 256, 0, stream>>>(QKbuf, offs, srcCSR, alphaW, Np0, C, hc, scale);
        }

        // V|S GEMM reuses QKbuf (Y / Q|K dead after alpha)
        {
            int tot = Np1 << kshift[l];
            prep2<<<(tot + 255) / 256, 256, 0, stream>>>(LW[l].vw, LW[l].vb, hc,
                                                         LW[l].sw, LW[l].sb, C,
                                                         BtVS, biasVS, K, kshift[l], Np1);
        }
        dim3 gvs(grid_m, Np1 / 128);
        gemm128<<<gvs, 256, 0, stream>>>(Acur, K, 0, BtVS, K, 0, biasVS,
                                         QKbuf, Np1, 0, Sf, NN, Np1, K, hc, C);

        node_agg<<<NN, 256, 0, stream>>>(QKbuf, Sf, offs, srcCSR, alphaW, hf, houth,
                                         C, hc, Np1, l == 2 ? 1 : 0);
        Acur = houth;
    }

    pool_graph<<<NG, 256, 0, stream>>>(hf, gate_w, gate_b, fc_w, fc_b, goffs, gbuf, (float*)d_out);
}

// Round 11
// 580.054 us; speedup vs baseline: 1.2361x; 1.2361x over previous
//
#include <hip/hip_runtime.h>
#include <stdint.h>
#include <math.h>

#define NN 10000
#define NE 30000
#define NG 50
#define NH 8

typedef _Float16 f16;
typedef _Float16 f16x2 __attribute__((ext_vector_type(2)));
typedef _Float16 f16x4 __attribute__((ext_vector_type(4)));
typedef _Float16 f16x8 __attribute__((ext_vector_type(8)));
typedef float f32x4 __attribute__((ext_vector_type(4)));

// ---------------- helpers ----------------
__device__ inline void async16(f16* l, const f16* g) {
    __builtin_amdgcn_global_load_lds((const __attribute__((address_space(1))) void*)g,
                                     (__attribute__((address_space(3))) void*)l, 16, 0, 0);
}

// ---------------- CSR build ----------------
__global__ void hist_kernel(const int* __restrict__ dst, int* __restrict__ deg, int E) {
    int e = blockIdx.x * blockDim.x + threadIdx.x;
    if (e < E) atomicAdd(&deg[dst[e]], 1);
}

__global__ __launch_bounds__(1024) void scan_kernel(const int* __restrict__ deg, int* __restrict__ offs, int n) {
    __shared__ int tmp[1024];
    __shared__ int carry;
    if (threadIdx.x == 0) { carry = 0; offs[0] = 0; }
    __syncthreads();
    for (int base = 0; base < n; base += 1024) {
        int i = base + (int)threadIdx.x;
        int v = (i < n) ? deg[i] : 0;
        tmp[threadIdx.x] = v;
        __syncthreads();
        for (int d = 1; d < 1024; d <<= 1) {
            int t = 0;
            if ((int)threadIdx.x >= d) t = tmp[threadIdx.x - d];
            __syncthreads();
            if ((int)threadIdx.x >= d) tmp[threadIdx.x] += t;
            __syncthreads();
        }
        if (i < n) offs[i + 1] = carry + tmp[threadIdx.x];
        __syncthreads();
        if (threadIdx.x == 0) carry += tmp[1023];
        __syncthreads();
    }
}

__global__ void copy_int(const int* __restrict__ a, int* __restrict__ b, int n) {
    int i = blockIdx.x * blockDim.x + threadIdx.x;
    if (i < n) b[i] = a[i];
}

__global__ void scatter_kernel(const int* __restrict__ src, const int* __restrict__ dst,
                               int* __restrict__ cursor, int* __restrict__ srcCSR, int E) {
    int e = blockIdx.x * blockDim.x + threadIdx.x;
    if (e < E) {
        int p = atomicAdd(&cursor[dst[e]], 1);
        srcCSR[p] = src[e];
    }
}

// per-segment insertion sort -> deterministic CSR (fixed fp32 summation orders)
__global__ void sort_csr(const int* __restrict__ offs, int* __restrict__ srcCSR) {
    int n = blockIdx.x * blockDim.x + threadIdx.x;
    if (n >= NN) return;
    int s = offs[n], e = offs[n + 1];
    for (int i = s + 1; i < e; ++i) {
        int v = srcCSR[i];
        int j = i - 1;
        while (j >= s && srcCSR[j] > v) { srcCSR[j + 1] = srcCSR[j]; --j; }
        srcCSR[j + 1] = v;
    }
}

__global__ void goffs_kernel(const int* __restrict__ batch, int* __restrict__ goffs) {
    int g = threadIdx.x;
    if (g > NG) return;
    int lo = 0, hi = NN;
    while (lo < hi) {
        int mid = (lo + hi) >> 1;
        if (batch[mid] < g) lo = mid + 1; else hi = mid;
    }
    goffs[g] = lo;
}

// ---------------- conversions / weight prep ----------------
__global__ void cvt_f16_kernel(const float* __restrict__ in, f16* __restrict__ out, int n) {
    int i = blockIdx.x * blockDim.x + threadIdx.x;
    if (i < n) out[i] = (f16)in[i];
}

// Build Bt [Ntot][K] f16 (transposed, concatenated W0|W1|zero-pad) + bias [Ntot] f32.
__global__ void prep2(const float* __restrict__ W0, const float* __restrict__ b0, int n0,
                      const float* __restrict__ W1, const float* __restrict__ b1, int n1,
                      f16* __restrict__ Bt, float* __restrict__ bias,
                      int K, int kshift, int Ntot) {
    int tid = blockIdx.x * blockDim.x + threadIdx.x;
    if (tid >= (Ntot << kshift)) return;
    int n = tid >> kshift;
    int k = tid & (K - 1);
    float w = 0.0f;
    if (n < n0) w = W0[(size_t)k * n0 + n];
    else if (n < n0 + n1) w = W1[(size_t)k * n1 + (n - n0)];
    Bt[tid] = (f16)w;
    if (k == 0) bias[n] = (n < n0) ? b0[n] : ((n < n0 + n1) ? b1[n - n0] : 0.0f);
}

// u/v rows of the Y transform, ONE WAVE PER OUTPUT (k,h,isV): 2048 waves, wave-
// reduce over C. row 8fin+h = Wq_h@kb_h (bias c_h = qb_h.kb_h); row 8fin+8+h =
// Wk_h@qb_h (bias 0). First 8 waves also reduce c_h.
__global__ __launch_bounds__(256) void prepU(const float* __restrict__ qw, const float* __restrict__ qb,
                                             const float* __restrict__ kw, const float* __restrict__ kb,
                                             f16* __restrict__ BtY, float* __restrict__ biasY,
                                             int fin, int hc, int C) {
    const int wid = blockIdx.x * 4 + ((int)threadIdx.x >> 6);
    const int lane = threadIdx.x & 63;
    if (wid >= fin * 16) return;
    const int k = wid >> 4;
    const int idx = wid & 15;
    const int h = idx & 7, isV = idx >> 3;
    const float* W = isV ? kw : qw;
    const float* bvec = isV ? qb : kb;
    float s = 0.0f;
    for (int c = lane; c < C; c += 64) s += W[(size_t)k * hc + h * C + c] * bvec[h * C + c];
#pragma unroll
    for (int o = 32; o > 0; o >>= 1) s += __shfl_down(s, o, 64);
    if (lane == 0) BtY[(size_t)(8 * fin + isV * 8 + h) * fin + k] = (f16)s;
    if (wid < 8) {   // k==0, isV==0, h==wid: also compute c_h
        float cc = 0.0f;
        for (int c = lane; c < C; c += 64) cc += qb[wid * C + c] * kb[wid * C + c];
#pragma unroll
        for (int o = 32; o > 0; o >>= 1) cc += __shfl_down(cc, o, 64);
        if (lane == 0) biasY[8 * fin + wid] = cc;
    }
}

// ---------------- GEMM: C[M,Np] = A @ Bt^T + bias, f16 out (generalized strides) ----
// 128x128 tile, BK=32, 3-stage ring prefetch (distance 2), s_waitcnt vmcnt(4) +
// raw s_barrier (prefetch survives the barrier), XOR-swizzled k-chunks,
// swapped-operand MFMA, union-LDS epilogue. Per-z offsets for batched (per-head) use.
__global__ __launch_bounds__(256) void gemm128(const f16* __restrict__ A, int lda, int zA,
                                               const f16* __restrict__ Bt, int ldb, int zB,
                                               const float* __restrict__ bias,
                                               f16* __restrict__ C, int ldc, int zC,
                                               float* __restrict__ Sf,
                                               int M, int Np, int K, int hcS, int Sw) {
    __shared__ f16 smem[24576];   // 48 KB = 3 stages x (A 4096 + B 4096 f16)
    const int rm = blockIdx.x * 128;
    if (rm >= M) return;          // padded grid column (XCD-stable mapping)
    A  += (size_t)blockIdx.z * zA;
    Bt += (size_t)blockIdx.z * zB;
    C  += (size_t)blockIdx.z * zC;
    const int tid  = threadIdx.x;
    const int lane = tid & 63;
    const int wave = tid >> 6;
    const int l16  = lane & 15;
    const int quad = lane >> 4;
    const int cn   = blockIdx.y * 128;
    const int wrow = (wave >> 1) * 64;
    const int wcol = (wave & 1) * 64;

    const int rS  = tid >> 2;
    const int kc  = ((tid & 3) ^ ((tid >> 3) & 3)) << 3;
    int rowA0 = rm + rS;       if (rowA0 >= M) rowA0 = M - 1;
    int rowA1 = rm + rS + 64;  if (rowA1 >= M) rowA1 = M - 1;
    const f16* gA0 = A + (size_t)rowA0 * lda + kc;
    const f16* gA1 = A + (size_t)rowA1 * lda + kc;
    const f16* gB0 = Bt + (size_t)(cn + rS) * ldb + kc;
    const f16* gB1 = Bt + (size_t)(cn + rS + 64) * ldb + kc;

    const int swf = (l16 >> 1) & 3;
    const int rdAoff = (wrow + l16) * 32 + ((quad ^ swf) << 3);
    const int rdBoff = 4096 + (wcol + l16) * 32 + ((quad ^ swf) << 3);

    f32x4 acc[4][4] = {};

    auto stage_load = [&](int slot) {
        f16* base = smem + slot * 8192;
        async16(base + tid * 8, gA0);
        async16(base + tid * 8 + 2048, gA1);
        async16(base + 4096 + tid * 8, gB0);
        async16(base + 4096 + tid * 8 + 2048, gB1);
        gA0 += 32; gA1 += 32; gB0 += 32; gB1 += 32;
    };

    const int NI = K >> 5;
    stage_load(0);
    stage_load(1);

    int slot = 0;
    for (int i = 0; i < NI; ++i) {
        if (i + 1 < NI) asm volatile("s_waitcnt vmcnt(4)" ::: "memory");
        else            asm volatile("s_waitcnt vmcnt(0)" ::: "memory");
        asm volatile("s_barrier" ::: "memory");
        if (i + 2 < NI) {
            int s2 = slot + 2; if (s2 >= 3) s2 -= 3;
            stage_load(s2);
        }
        const f16* sb = smem + slot * 8192;
        f16x8 av[4], bv[4];
#pragma unroll
        for (int ii = 0; ii < 4; ++ii) av[ii] = *(const f16x8*)(sb + rdAoff + ii * 512);
#pragma unroll
        for (int j = 0; j < 4; ++j) bv[j] = *(const f16x8*)(sb + rdBoff + j * 512);
#pragma unroll
        for (int ii = 0; ii < 4; ++ii)
#pragma unroll
            for (int j = 0; j < 4; ++j)
                acc[ii][j] = __builtin_amdgcn_mfma_f32_16x16x32_f16(bv[j], av[ii], acc[ii][j], 0, 0, 0);
        ++slot; if (slot == 3) slot = 0;
    }
    __syncthreads();

    f16* sC = smem;    // 64 x 136 f16
    for (int round = 0; round < 2; ++round) {
        if ((wave >> 1) == round) {
#pragma unroll
            for (int j = 0; j < 4; ++j) {
                const int cb = wcol + j * 16 + quad * 4;
                const float4 bb = *(const float4*)(bias + cn + cb);
#pragma unroll
                for (int i = 0; i < 4; ++i) {
                    const int r = i * 16 + l16;
                    float v0 = acc[i][j][0] + bb.x;
                    float v1 = acc[i][j][1] + bb.y;
                    float v2 = acc[i][j][2] + bb.z;
                    float v3 = acc[i][j][3] + bb.w;
                    f16x4 o;
                    o[0] = (f16)v0; o[1] = (f16)v1; o[2] = (f16)v2; o[3] = (f16)v3;
                    *(f16x4*)(sC + r * 136 + cb) = o;
                    if (Sf) {
                        const int sc = cn + cb - hcS;
                        if (sc >= 0 && sc < Sw) {
                            const int grow = rm + round * 64 + r;
                            if (grow < M) {
                                float4 sv = { v0, v1, v2, v3 };
                                *(float4*)(Sf + (size_t)grow * Sw + sc) = sv;
                            }
                        }
                    }
                }
            }
        }
        __syncthreads();
#pragma unroll
        for (int it = 0; it < 4; ++it) {
            const int r = it * 16 + (tid >> 4);
            const int ch = tid & 15;
            const int grow = rm + round * 64 + r;
            if (grow < M) {
                f16x8 v = *(const f16x8*)(sC + r * 136 + ch * 8);
                *(f16x8*)(C + (size_t)grow * ldc + cn + ch * 8) = v;
            }
        }
        __syncthreads();
    }
}

// ---------------- layer-1 alpha via Y = X@M_h trick ----------------
// alpha[e,h] = scale * ( Y_h[n] . x[src] + u[n,h] + v[src,h] )   (c_h folded in u bias)
__global__ __launch_bounds__(256) void alpha_fused_y(const f16* __restrict__ Y, const f16* __restrict__ X,
                                                     const int* __restrict__ offs,
                                                     const int* __restrict__ srcCSR,
                                                     float* __restrict__ alphaW,
                                                     int strideY, int fin, float scale) {
    const int n = blockIdx.x;
    const int e0 = offs[n];
    int d = offs[n + 1] - e0;
    if (d > 256) d = 256;

    __shared__ __align__(16) f16 sy[1024];   // 8*fin (fin=128)
    __shared__ float sew[256 * NH];
    __shared__ float sv[256 * NH];
    __shared__ int sed[256];
    __shared__ float su[NH];
    const int tid = threadIdx.x;

    const f16* Yn = Y + (size_t)n * strideY;
    for (int c = tid; c < fin; c += 256) ((f16x8*)sy)[c] = ((const f16x8*)Yn)[c];
    if (tid < NH) su[tid] = (float)Yn[8 * fin + tid];
    for (int e = tid; e < d; e += 256) {
        int s = srcCSR[e0 + e];
        sed[e] = s;
        f16x8 vv = *(const f16x8*)(Y + (size_t)s * strideY + 8 * fin + 8);
#pragma unroll
        for (int t = 0; t < 8; ++t) sv[e * NH + t] = (float)vv[t];
    }
    __syncthreads();

    const int wv = tid >> 6, lane = tid & 63;
    const int cph = fin >> 3;          // x-chunks per head (16 for fin=128)
    const int csh = __ffs(cph) - 1;
    const int passes = fin >> 6;
    for (int e = wv; e < d; e += 4) {
        const f16x8* kg = (const f16x8*)(X + (size_t)sed[e] * fin);
        for (int p = 0; p < passes; ++p) {
            const int ci = p * 64 + lane;
            const int head = ci >> csh;
            const int kcn = ci & (cph - 1);
            f16x8 yv = ((const f16x8*)sy)[ci];
            f16x8 xv = kg[kcn];
            float acc = 0.0f;
#pragma unroll
            for (int t = 0; t < 8; ++t) acc += (float)yv[t] * (float)xv[t];
            for (int o = cph >> 1; o > 0; o >>= 1) acc += __shfl_down(acc, o, cph);
            if ((lane & (cph - 1)) == 0)
                sew[e * NH + head] = (acc + su[head] + sv[e * NH + head]) * scale;
        }
    }
    __syncthreads();

    if (tid < NH) {
        const int h = tid;
        float m = -3.0e38f;
        for (int e = 0; e < d; ++e) m = fmaxf(m, sew[e * NH + h]);
        float den = 0.0f;
        for (int e = 0; e < d; ++e) {
            float ex = __expf(sew[e * NH + h] - m);
            sew[e * NH + h] = ex;
            den += ex;
        }
        float inv = 1.0f / (fmaxf(den, 1e-16f) * (float)NH);
        for (int e = 0; e < d; ++e) sew[e * NH + h] *= inv;
    }
    __syncthreads();

    for (int i = tid; i < d * NH; i += 256) alphaW[(size_t)e0 * NH + i] = sew[i];
}

// ---------------- layers 2,3: edge logits + softmax from materialized Q|K ----------
__global__ __launch_bounds__(256) void alpha_fused(const f16* __restrict__ QK,
                                                   const int* __restrict__ offs,
                                                   const int* __restrict__ srcCSR,
                                                   float* __restrict__ alphaW,
                                                   int strideQK, int C, int hc, float scale) {
    const int n = blockIdx.x;
    const int e0 = offs[n];
    int d = offs[n + 1] - e0;
    if (d > 256) d = 256;

    __shared__ __align__(16) f16 sq[4096];
    __shared__ float sew[256 * NH];
    __shared__ int sed[256];
    const int tid = threadIdx.x;

    const f16x8* qg = (const f16x8*)(QK + (size_t)n * strideQK);
    const int qchunks = hc >> 3;
    for (int c = tid; c < qchunks; c += 256) ((f16x8*)sq)[c] = qg[c];
    for (int e = tid; e < d; e += 256) sed[e] = srcCSR[e0 + e];
    __syncthreads();

    const int wv = tid >> 6, lane = tid & 63;
    const int cph = C >> 3;
    const int passes = hc >> 9;
    for (int e = wv; e < d; e += 4) {
        const f16x8* kg = (const f16x8*)(QK + (size_t)sed[e] * strideQK + hc);
        for (int p = 0; p < passes; ++p) {
            const int ci = p * 64 + lane;
            f16x8 qv = ((const f16x8*)sq)[ci];
            f16x8 kv = kg[ci];
            float acc = 0.0f;
#pragma unroll
            for (int t = 0; t < 8; ++t) acc += (float)qv[t] * (float)kv[t];
            for (int o = cph >> 1; o > 0; o >>= 1) acc += __shfl_down(acc, o, cph);
            if ((lane & (cph - 1)) == 0) {
                const int head = ci / cph;
                sew[e * NH + head] = acc * scale;
            }
        }
    }
    __syncthreads();

    if (tid < NH) {
        const int h = tid;
        float m = -3.0e38f;
        for (int e = 0; e < d; ++e) m = fmaxf(m, sew[e * NH + h]);
        float den = 0.0f;
        for (int e = 0; e < d; ++e) {
            float ex = __expf(sew[e * NH + h] - m);
            sew[e * NH + h] = ex;
            den += ex;
        }
        float inv = 1.0f / (fmaxf(den, 1e-16f) * (float)NH);
        for (int e = 0; e < d; ++e) sew[e * NH + h] *= inv;
    }
    __syncthreads();

    for (int i = tid; i < d * NH; i += 256) alphaW[(size_t)e0 * NH + i] = sew[i];
}

// ---------------- per-node: weighted V aggregation + fp32 skip + ELU ----------------
__global__ __launch_bounds__(256) void node_agg(const f16* __restrict__ VS,
                                                const float* __restrict__ Sf,
                                                const int* __restrict__ offs,
                                                const int* __restrict__ srcCSR,
                                                const float* __restrict__ alphaW,
                                                float* __restrict__ hout, f16* __restrict__ houth,
                                                int C, int hc, int NpVS, int writeHout) {
    const int n = blockIdx.x;
    const int e0 = offs[n];
    int d = offs[n + 1] - e0;
    if (d > 256) d = 256;

    __shared__ float sew[256 * NH];
    __shared__ int sed[256];
    __shared__ float sred[512];
    const int tid = threadIdx.x;

    for (int i = tid; i < d * NH; i += 256) sew[i] = alphaW[(size_t)e0 * NH + i];
    for (int e = tid; e < d; e += 256) sed[e] = srcCSR[e0 + e];
    __syncthreads();

    const int half = C >> 1;
    const int cp = tid & (half - 1);
    const int grp = tid / half;
    const int ngr = 256 / half;
    float a0 = 0.0f, a1 = 0.0f;
    for (int e = grp; e < d; e += ngr) {
        const unsigned int* vp = (const unsigned int*)(VS + (size_t)sed[e] * NpVS);
#pragma unroll
        for (int h = 0; h < NH; ++h) {
            float w = sew[e * NH + h];
            f16x2 vv = __builtin_bit_cast(f16x2, vp[((h * C) >> 1) + cp]);
            a0 += w * (float)vv.x;
            a1 += w * (float)vv.y;
        }
    }
    if (ngr > 1) {
        sred[tid] = a0;
        sred[256 + tid] = a1;
        __syncthreads();
        if (grp == 0) {
            for (int g = 1; g < ngr; ++g) {
                a0 += sred[g * half + cp];
                a1 += sred[256 + g * half + cp];
            }
        }
    }
    if (grp == 0) {
        const int c = cp * 2;
        const float* Sp = Sf + (size_t)n * C;
        float o0 = a0 + Sp[c];
        float o1 = a1 + Sp[c + 1];
        o0 = o0 > 0.0f ? o0 : (__expf(o0) - 1.0f);
        o1 = o1 > 0.0f ? o1 : (__expf(o1) - 1.0f);
        if (writeHout) {
            hout[(size_t)n * C + c] = o0;
            hout[(size_t)n * C + c + 1] = o1;
        }
        houth[(size_t)n * C + c] = (f16)o0;
        houth[(size_t)n * C + c + 1] = (f16)o1;
    }
}

// ---------------- fused pooling + final FC: one block per graph, no atomics ----
__global__ __launch_bounds__(256) void pool_graph(const float* __restrict__ h,
                                                  const float* __restrict__ gw, const float* __restrict__ gb,
                                                  const float* __restrict__ fcw, const float* __restrict__ fcb,
                                                  const int* __restrict__ goffs,
                                                  float* __restrict__ gbuf, float* __restrict__ out) {
    const int g = blockIdx.x;
    const int s = goffs[g], e = goffs[g + 1];
    const int tid = threadIdx.x;
    const int wv = tid >> 6, lane = tid & 63;

    __shared__ float red[256];
    __shared__ float pl[64];
    __shared__ float sden;

    if (e == s) {
        if (tid < 10) out[g * 10 + tid] = fcb[tid];
        return;
    }

    const float gwl = gw[lane];
    for (int n = s + wv; n < e; n += 4) {
        float acc = h[(size_t)n * 64 + lane] * gwl;
#pragma unroll
        for (int o = 32; o > 0; o >>= 1) acc += __shfl_down(acc, o, 64);
        if (lane == 0) gbuf[n] = acc + gb[0];
    }
    __syncthreads();

    float m = -3.0e38f;
    for (int n = s + tid; n < e; n += 256) m = fmaxf(m, gbuf[n]);
    red[tid] = m;
    __syncthreads();
    for (int o = 128; o > 0; o >>= 1) {
        if (tid < o) red[tid] = fmaxf(red[tid], red[tid + o]);
        __syncthreads();
    }
    m = red[0];
    __syncthreads();

    float sum = 0.0f;
    for (int n = s + tid; n < e; n += 256) {
        float ex = __expf(gbuf[n] - m);
        gbuf[n] = ex;
        sum += ex;
    }
    red[tid] = sum;
    __syncthreads();
    for (int o = 128; o > 0; o >>= 1) {
        if (tid < o) red[tid] += red[tid + o];
        __syncthreads();
    }
    if (tid == 0) sden = 1.0f / fmaxf(red[0], 1e-16f);
    __syncthreads();

    float acc = 0.0f;
    for (int n = s + wv; n < e; n += 4) acc += gbuf[n] * h[(size_t)n * 64 + lane];
    red[tid] = acc;
    __syncthreads();
    if (wv == 0) pl[lane] = (red[lane] + red[64 + lane] + red[128 + lane] + red[192 + lane]) * sden;
    __syncthreads();

    if (tid < 10) {
        float o = fcb[tid];
#pragma unroll
        for (int c = 0; c < 64; ++c) o += pl[c] * fcw[c * 10 + tid];
        out[g * 10 + tid] = o;
    }
}

// ---------------- host ----------------
extern "C" void kernel_launch(void* const* d_in, const int* in_sizes, int n_in,
                              void* d_out, int out_size, void* d_ws, size_t ws_size,
                              hipStream_t stream) {
    const float* x   = (const float*)d_in[0];
    const int* ei    = (const int*)d_in[1];
    const int* src   = ei;
    const int* dst   = ei + NE;
    const int* batch = (const int*)d_in[2];

    struct LayerW { int fin, C, hc; const float *qw,*qb,*kw,*kb,*vw,*vb,*sw,*sb; };
    LayerW LW[3];
    const int fins[3]   = {128, 512, 256};
    const int kshift[3] = {7, 9, 8};
    const int Cs[3]     = {512, 256, 64};
    const int NpVS[3]   = {4608, 2304, 640};  // hc + C padded to x128
    for (int l = 0; l < 3; ++l) {
        int b = 3 + 8 * l;
        LW[l].fin = fins[l]; LW[l].C = Cs[l]; LW[l].hc = Cs[l] * NH;
        LW[l].qw = (const float*)d_in[b + 0]; LW[l].qb = (const float*)d_in[b + 1];
        LW[l].kw = (const float*)d_in[b + 2]; LW[l].kb = (const float*)d_in[b + 3];
        LW[l].vw = (const float*)d_in[b + 4]; LW[l].vb = (const float*)d_in[b + 5];
        LW[l].sw = (const float*)d_in[b + 6]; LW[l].sb = (const float*)d_in[b + 7];
    }
    const float* gate_w = (const float*)d_in[27];
    const float* gate_b = (const float*)d_in[28];
    const float* fc_w   = (const float*)d_in[29];
    const float* fc_b   = (const float*)d_in[30];

    size_t off = 0;
    char* ws = (char*)d_ws;
    auto alloc = [&](size_t bytes) -> void* {
        void* p = ws + off;
        off = (off + bytes + 255) & ~(size_t)255;
        return p;
    };
    f16* BtQK   = (f16*)alloc((size_t)4096 * 512 * sizeof(f16));
    f16* BtVS   = (f16*)alloc((size_t)2304 * 512 * sizeof(f16));
    float* biasQK = (float*)alloc(8192 * sizeof(float));
    float* biasVS = (float*)alloc(4608 * sizeof(float));
    f16* QKbuf  = (f16*)alloc((size_t)NN * 4608 * sizeof(f16));    // Y / Q|K / V|S (per phase)
    float* Sf   = (float*)alloc((size_t)NN * 512 * sizeof(float)); // fp32 skip
    f16* xh     = (f16*)alloc((size_t)NN * 128 * sizeof(f16));
    f16* houth  = (f16*)alloc((size_t)NN * 512 * sizeof(f16));
    float* hf   = (float*)alloc((size_t)NN * 64 * sizeof(float));
    float* alphaW = (float*)alloc((size_t)NE * NH * sizeof(float));
    f16* qw16   = (f16*)alloc((size_t)128 * 4096 * sizeof(f16));   // layer-1 Wq f16 row-major
    f16* kw16   = (f16*)alloc((size_t)128 * 4096 * sizeof(f16));
    f16* BtY    = (f16*)alloc((size_t)1152 * 128 * sizeof(f16));   // M rows + u/v rows
    float* biasY = (float*)alloc(1152 * sizeof(float));
    float* zbias = (float*)alloc(512 * sizeof(float));
    int* deg    = (int*)alloc(NN * sizeof(int));
    int* offs   = (int*)alloc((NN + 1) * sizeof(int));
    int* cursor = (int*)alloc(NN * sizeof(int));
    int* srcCSR = (int*)alloc(NE * sizeof(int));
    int* goffs  = (int*)alloc((NG + 1) * sizeof(int));
    float* gbuf = (float*)alloc(NN * sizeof(float));
    if (off > ws_size) return;

    // CSR build (+ deterministic sort) + graph offsets
    hipMemsetAsync(deg, 0, NN * sizeof(int), stream);
    hipMemsetAsync(zbias, 0, 512 * sizeof(float), stream);
    hipMemsetAsync(biasY, 0, 1152 * sizeof(float), stream);
    hist_kernel<<<(NE + 255) / 256, 256, 0, stream>>>(dst, deg, NE);
    scan_kernel<<<1, 1024, 0, stream>>>(deg, offs, NN);
    copy_int<<<(NN + 255) / 256, 256, 0, stream>>>(offs, cursor, NN);
    scatter_kernel<<<(NE + 255) / 256, 256, 0, stream>>>(src, dst, cursor, srcCSR, NE);
    sort_csr<<<(NN + 255) / 256, 256, 0, stream>>>(offs, srcCSR);
    goffs_kernel<<<1, 64, 0, stream>>>(batch, goffs);

    cvt_f16_kernel<<<(NN * 128 + 255) / 256, 256, 0, stream>>>(x, xh, NN * 128);

    const int grid_m = 80;   // mult of 8: XCD = blockIdx.x % 8 invariant across y-passes
    const f16* Acur = xh;
    for (int l = 0; l < 3; ++l) {
        const int K = LW[l].fin, C = LW[l].C, hc = LW[l].hc;
        const int Np1 = NpVS[l];
        const float scale = 1.0f / sqrtf((float)C);

        if (l == 0) {
            // ---- layer 1: Y = X @ [M_h | u | v] trick (fin=128 << hc=4096) ----
            const int fin = 128, NtotY = 1152;
            cvt_f16_kernel<<<(fin * hc + 255) / 256, 256, 0, stream>>>(LW[0].qw, qw16, fin * hc);
            cvt_f16_kernel<<<(fin * hc + 255) / 256, 256, 0, stream>>>(LW[0].kw, kw16, fin * hc);
            // M rows: BtY[h*fin+j, k] = sum_c kw[j,hC+c] qw[k,hC+c]  (per-head GEMM via z)
            dim3 gm(1, 1, 8);
            gemm128<<<gm, 256, 0, stream>>>(kw16, hc, C, qw16, hc, C, zbias,
                                            BtY, fin, fin * fin, nullptr, fin, fin, C, 0, 0);
            prepU<<<(fin * 16 + 3) / 4, 256, 0, stream>>>(LW[0].qw, LW[0].qb, LW[0].kw, LW[0].kb,
                                                          BtY, biasY, fin, hc, C);
            // Y GEMM: [NN, NtotY]
            dim3 gy(grid_m, NtotY / 128);
            gemm128<<<gy, 256, 0, stream>>>(xh, fin, 0, BtY, fin, 0, biasY,
                                            QKbuf, NtotY, 0, nullptr, NN, NtotY, fin, 0, 0);
            alpha_fused_y<<<NN, 256, 0, stream>>>(QKbuf, xh, offs, srcCSR, alphaW,
                                                  NtotY, fin, scale);
        } else {
            // ---- layers 2,3: materialized Q|K path ----
            const int Np0 = 2 * hc;
            {
                int tot = Np0 << kshift[l];
                prep2<<<(tot + 255) / 256, 256, 0, stream>>>(LW[l].qw, LW[l].qb, hc,
                                                             LW[l].kw, LW[l].kb, hc,
                                                             BtQK, biasQK, K, kshift[l], Np0);
            }
            dim3 gqk(grid_m, Np0 / 128);
            gemm128<<<gqk, 256, 0, stream>>>(Acur, K, 0, BtQK, K, 0, biasQK,
                                             QKbuf, Np0, 0, nullptr, NN, Np0, K, 0, 0);
            alpha_fused<<<NN, 256, 0, stream>>>(QKbuf, offs, srcCSR, alphaW, Np0, C, hc, scale);
        }

        // V|S GEMM reuses QKbuf (Y / Q|K dead after alpha)
        {
            int tot = Np1 << kshift[l];
            prep2<<<(tot + 255) / 256, 256, 0, stream>>>(LW[l].vw, LW[l].vb, hc,
                                                         LW[l].sw, LW[l].sb, C,
                                                         BtVS, biasVS, K, kshift[l], Np1);
        }
        dim3 gvs(grid_m, Np1 / 128);
        gemm128<<<gvs, 256, 0, stream>>>(Acur, K, 0, BtVS, K, 0, biasVS,
                                         QKbuf, Np1, 0, Sf, NN, Np1, K, hc, C);

        node_agg<<<NN, 256, 0, stream>>>(QKbuf, Sf, offs, srcCSR, alphaW, hf, houth,
                                         C, hc, Np1, l == 2 ? 1 : 0);
        Acur = houth;
    }

    pool_graph<<<NG, 256, 0, stream>>>(hf, gate_w, gate_b, fc_w, fc_b, goffs, gbuf, (float*)d_out);
}